// Round 1
// baseline (44.315 us; speedup 1.0000x reference)
//
#include <hip/hip_runtime.h>
#include <math.h>

// Problem constants (from reference: x = (2,2,160,160,160) fp32)
#define BCn 4
#define Dn 160
#define Hn 160
#define Wn 160
#define HWn (Hn * Wn)
#define DCHUNK 32

// Load one z-plane's 3x3 neighborhood row-sums (R*) and W-differences (C*)
// for this thread's column (h,w), with replicate clamping on all axes.
#define LOADPLANE(zz, Rm, Rc, Rp, Cm, Cc, Cp)                      \
  do {                                                             \
    int zc_ = (zz) < 0 ? 0 : ((zz) > Dn - 1 ? Dn - 1 : (zz));      \
    const float* p_ = xb + (size_t)zc_ * HWn;                      \
    float am_, ac_, ap_;                                           \
    am_ = p_[rm + wm]; ac_ = p_[rm + w]; ap_ = p_[rm + wp];        \
    Rm = am_ + ac_ + ap_; Cm = ap_ - am_;                          \
    am_ = p_[r0 + wm]; ac_ = p_[r0 + w]; ap_ = p_[r0 + wp];        \
    Rc = am_ + ac_ + ap_; Cc = ap_ - am_;                          \
    am_ = p_[rp + wm]; ac_ = p_[rp + w]; ap_ = p_[rp + wp];        \
    Rp = am_ + ac_ + ap_; Cp = ap_ - am_;                          \
  } while (0)

__global__ __launch_bounds__(256) void sobel3d_mag_kernel(
    const float* __restrict__ x, float* __restrict__ out) {
  const int col = blockIdx.x * 256 + threadIdx.x;
  if (col >= HWn) return;
  const int h = col / Wn;
  const int w = col - h * Wn;
  const int bc = blockIdx.z;
  const int d0 = blockIdx.y * DCHUNK;
  const int d1 = d0 + DCHUNK;

  const float* xb = x + (size_t)bc * Dn * HWn;
  float* ob = out + (size_t)bc * Dn * HWn;

  // Replicate-clamped neighbor indices
  const int wm = (w > 0) ? w - 1 : 0;
  const int wp = (w < Wn - 1) ? w + 1 : Wn - 1;
  const int hm = (h > 0) ? h - 1 : 0;
  const int hp = (h < Hn - 1) ? h + 1 : Hn - 1;
  const int rm = hm * Wn;
  const int r0 = h * Wn;
  const int rp = hp * Wn;

  // Rolling 3-plane state: plane 0 = z-1, plane 1 = z, plane 2 = z+1.
  // Explicit named registers (no runtime-indexed arrays -> no scratch).
  float R0m, R0c, R0p, C0m, C0c, C0p;
  float R1m, R1c, R1p, C1m, C1c, C1p;
  float R2m, R2c, R2p, C2m, C2c, C2p;

  LOADPLANE(d0 - 1, R0m, R0c, R0p, C0m, C0c, C0p);
  LOADPLANE(d0,     R1m, R1c, R1p, C1m, C1c, C1p);

  for (int z = d0; z < d1; ++z) {
    LOADPLANE(z + 1, R2m, R2c, R2p, C2m, C2c, C2p);

    // g along D: full 3x3 plane-sum difference between z+1 and z-1
    const float gd = (R2m + R2c + R2p) - (R0m + R0c + R0p);
    // g along H: (row h+1 sum) - (row h-1 sum), accumulated over all 3 z
    const float gh = (R0p - R0m) + (R1p - R1m) + (R2p - R2m);
    // g along W: (w+1) - (w-1) differences, accumulated over 3 rows x 3 z
    const float gw = (C0m + C0c + C0p) + (C1m + C1c + C1p) + (C2m + C2c + C2p);

    ob[(size_t)z * HWn + col] = sqrtf(gd * gd + gh * gh + gw * gw);

    // Shift the rolling planes
    R0m = R1m; R0c = R1c; R0p = R1p; C0m = C1m; C0c = C1c; C0p = C1p;
    R1m = R2m; R1c = R2c; R1p = R2p; C1m = C2m; C1c = C2c; C1p = C2p;
  }
}

extern "C" void kernel_launch(void* const* d_in, const int* in_sizes, int n_in,
                              void* d_out, int out_size, void* d_ws, size_t ws_size,
                              hipStream_t stream) {
  const float* x = (const float*)d_in[0];
  float* out = (float*)d_out;

  dim3 block(256);
  dim3 grid((HWn + 255) / 256, Dn / DCHUNK, BCn);  // (100, 5, 4)
  sobel3d_mag_kernel<<<grid, block, 0, stream>>>(x, out);
}